// Round 8
// baseline (439.229 us; speedup 1.0000x reference)
//
#include <hip/hip_runtime.h>
#include <hip/hip_fp16.h>

// Problem constants
#define NV    884736     // 96^3 voxels
#define NB    3456       // NV / 256
#define DIM   96
#define DIM2  9216       // 96*96

// Fields stored as half4 (x,y,z,pad) = 8 B/voxel. A z-adjacent voxel PAIR is
// 16 contiguous bytes. Trilinear combine runs in packed f16 (v_pk_fma_f16).
//
// R7 lesson: the step kernel is an ADDITIVE multi-pipe wall (VALU+LDS+VMEM
// each ~proportional). This round cuts the VALU slice: column-walk mapping
// removes per-voxel index div/mods; own-voxel/store addresses increment.

union H4 { uint2 u; __half2 h2[2]; };   // one voxel (8 B): (x,y),(z,0)
struct H8 { __half2 h2[4]; };           // two z-adjacent voxels

__device__ __forceinline__ __half2 lerp_h2(__half2 lo, __half2 hi, __half2 t) {
    return __hfma2(t, __hsub2(hi, lo), lo);
}

__device__ __forceinline__ int clampi(int v) {
    return v < 0 ? 0 : (v > DIM - 1 ? DIM - 1 : v);
}

// Border semantics EXACTLY as the reference:
//   x0 = clamp((int)floor(x),0,95); x1 = min(x0+1,95); fx = x - floor(x) (unclamped)
// z edge: when z0==95 force wz=0 so the second voxel of the z-pair is
// multiplied by 0 (reference has c001==c000 there).
struct TriP { int x0, y0, z0, x1, y1; __half2 wx, wy, wz; };

__device__ __forceinline__ TriP tri_prep(float x, float y, float z) {
    TriP t;
    float xf = floorf(x), yf = floorf(y), zf = floorf(z);
    float fx = x - xf, fy = y - yf, fz = z - zf;
    int x0 = (int)xf; x0 = x0 < 0 ? 0 : (x0 > DIM - 1 ? DIM - 1 : x0);
    int y0 = (int)yf; y0 = y0 < 0 ? 0 : (y0 > DIM - 1 ? DIM - 1 : y0);
    int z0 = (int)zf; z0 = z0 < 0 ? 0 : (z0 > DIM - 1 ? DIM - 1 : z0);
    int x1 = x0 + 1; if (x1 > DIM - 1) x1 = DIM - 1;
    int y1 = y0 + 1; if (y1 > DIM - 1) y1 = DIM - 1;
    t.x0 = x0; t.y0 = y0; t.z0 = z0; t.x1 = x1; t.y1 = y1;
    t.wx = __float2half2_rn(fx);
    t.wy = __float2half2_rn(fy);
    t.wz = __float2half2_rn(z0 < DIM - 1 ? fz : 0.0f);
    return t;
}

__device__ __forceinline__ void tri_gather_global(const uint2* __restrict__ f,
                                                  const TriP& t, H8 c[4]) {
    int i00 = t.x0 * DIM2 + t.y0 * DIM + t.z0;
    int i01 = t.x0 * DIM2 + t.y1 * DIM + t.z0;
    int i10 = t.x1 * DIM2 + t.y0 * DIM + t.z0;
    int i11 = t.x1 * DIM2 + t.y1 * DIM + t.z0;
    *(uint4*)&c[0] = *(const uint4*)(f + i00);
    *(uint4*)&c[1] = *(const uint4*)(f + i01);
    *(uint4*)&c[2] = *(const uint4*)(f + i10);
    *(uint4*)&c[3] = *(const uint4*)(f + i11);
}

struct H2P { __half2 xy, z; };

__device__ __forceinline__ H2P tri_combine(const TriP& t, const H8 c[4]) {
    __half2 xy00 = lerp_h2(c[0].h2[0], c[0].h2[2], t.wz);
    __half2 z_00 = lerp_h2(c[0].h2[1], c[0].h2[3], t.wz);
    __half2 xy01 = lerp_h2(c[1].h2[0], c[1].h2[2], t.wz);
    __half2 z_01 = lerp_h2(c[1].h2[1], c[1].h2[3], t.wz);
    __half2 xy10 = lerp_h2(c[2].h2[0], c[2].h2[2], t.wz);
    __half2 z_10 = lerp_h2(c[2].h2[1], c[2].h2[3], t.wz);
    __half2 xy11 = lerp_h2(c[3].h2[0], c[3].h2[2], t.wz);
    __half2 z_11 = lerp_h2(c[3].h2[1], c[3].h2[3], t.wz);
    __half2 xy0 = lerp_h2(xy00, xy01, t.wy);
    __half2 z_0 = lerp_h2(z_00, z_01, t.wy);
    __half2 xy1 = lerp_h2(xy10, xy11, t.wy);
    __half2 z_1 = lerp_h2(z_10, z_11, t.wy);
    H2P r;
    r.xy = lerp_h2(xy0, xy1, t.wx);
    r.z  = lerp_h2(z_0, z_1, t.wx);
    return r;
}

// Init: v0 = +T/128 into fields 0..3, v0 = -T/128 into fields 4..7 (half4).
// Also zeroes the loss accumulator (d_out is poisoned before every timed launch).
__global__ __launch_bounds__(256) void init_kernel(const float* __restrict__ T,
                                                   uint2* __restrict__ bufA,
                                                   float* __restrict__ out) {
    int t = blockIdx.y;
    int l = blockIdx.x * 256 + threadIdx.x;
    if (t == 0 && l == 0) out[0] = 0.0f;
    const float inv = 1.0f / 128.0f;
    float vx = T[(size_t)(t * 3 + 0) * NV + l] * inv;
    float vy = T[(size_t)(t * 3 + 1) * NV + l] * inv;
    float vz = T[(size_t)(t * 3 + 2) * NV + l] * inv;
    H4 p; p.h2[0] = __floats2half2_rn( vx,  vy); p.h2[1] = __floats2half2_rn( vz, 0.0f);
    H4 n; n.h2[0] = __floats2half2_rn(-vx, -vy); n.h2[1] = __floats2half2_rn(-vz, 0.0f);
    bufA[(size_t)t * NV + l]       = p.u;
    bufA[(size_t)(t + 4) * NV + l] = n.u;
}

// Column-walk LDS step: tile 16(x) x CY(y) x 16(z), halo H per axis (+1 z for
// pair reads). Thread = (lz, lx) = (tid&15, tid>>4); walks y. Index decode is
// per-THREAD (not per-voxel); own-LDS / store addresses increment by LZ / DIM.
// Out-of-halo samples (never expected on this data; correctness must be
// data-independent) fall back to global gathers.
template<int H, int CY>
__global__ __launch_bounds__(256) void step_col_kernel(const uint2* __restrict__ src,
                                                       uint2* __restrict__ dst) {
    constexpr int LX = 16 + 2 * H;
    constexpr int LY = CY + 2 * H;
    constexpr int LZ = 16 + 2 * H + 1;   // +1 high-z for pair reads
    constexpr int SZ = LX * LY * LZ;
    constexpr int NTY = DIM / CY;
    __shared__ uint2 tile[SZ];

    int b = blockIdx.x;
    int f = b & 7;                         // field (XCD-affine)
    int t = b >> 3;
    int tz = t % 6;
    int t2 = t / 6;
    int ty = t2 % NTY;
    int tx = t2 / NTY;
    int gx0 = tx * 16, gy0 = ty * CY, gz0 = tz * 16;
    int ox = gx0 - H, oy = gy0 - H, oz = gz0 - H;

    const uint2* __restrict__ s = src + (size_t)f * NV;
    uint2*       __restrict__ d = dst + (size_t)f * NV;

    // Stage tile+halo (clamp-replicated); consecutive n -> consecutive z,
    // coalesced global reads.
    for (int n = threadIdx.x; n < SZ; n += 256) {
        int lz = n % LZ;
        int r  = n / LZ;
        int ly = r % LY;
        int lx = r / LY;
        tile[n] = s[clampi(ox + lx) * DIM2 + clampi(oy + ly) * DIM + clampi(oz + lz)];
    }
    __syncthreads();

    int lz = threadIdx.x & 15;
    int lx = threadIdx.x >> 4;
    int gi = gx0 + lx, gk = gz0 + lz;
    float fi = (float)gi, fk = (float)gk;
    int own  = ((lx + H) * LY + H) * LZ + (lz + H);
    int sidx = gi * DIM2 + gy0 * DIM + gk;

    for (int q = 0; q < CY; q++) {
        H4 v; v.u = tile[own];
        float2 vxy = __half22float2(v.h2[0]);
        float  vz  = __low2float(v.h2[1]);
        TriP p = tri_prep(fi + vxy.x, (float)(gy0 + q) + vxy.y, fk + vz);

        int a0 = p.x0 - ox, a1 = p.x1 - ox;
        int b0 = p.y0 - oy, b1 = p.y1 - oy;
        int c0 = p.z0 - oz;
        bool inb = (a0 >= 0) & (a1 <= LX - 1) &
                   (b0 >= 0) & (b1 <= LY - 1) &
                   (c0 >= 0) & (c0 <= LZ - 2);

        H8 c[4];
        if (inb) {
            int i00 = (a0 * LY + b0) * LZ + c0;
            int i01 = (a0 * LY + b1) * LZ + c0;
            int i10 = (a1 * LY + b0) * LZ + c0;
            int i11 = (a1 * LY + b1) * LZ + c0;
            uint2 A0 = tile[i00], A1 = tile[i00 + 1];
            uint2 B0 = tile[i01], B1 = tile[i01 + 1];
            uint2 C0 = tile[i10], C1 = tile[i10 + 1];
            uint2 D0 = tile[i11], D1 = tile[i11 + 1];
            *(uint4*)&c[0] = make_uint4(A0.x, A0.y, A1.x, A1.y);
            *(uint4*)&c[1] = make_uint4(B0.x, B0.y, B1.x, B1.y);
            *(uint4*)&c[2] = make_uint4(C0.x, C0.y, C1.x, C1.y);
            *(uint4*)&c[3] = make_uint4(D0.x, D0.y, D1.x, D1.y);
        } else {
            tri_gather_global(s, p, c);
        }
        H2P smp = tri_combine(p, c);
        H4 o;
        o.h2[0] = __hadd2(v.h2[0], smp.xy);
        o.h2[1] = __hadd2(v.h2[1], smp.z);
        d[sidx] = o.u;
        own  += LZ;
        sidx += DIM;
    }
}

// Plain-gather step (for step 6 where halo-3 staging redundancy is too big).
__global__ __launch_bounds__(256) void step_plain_kernel(const uint2* __restrict__ src,
                                                         uint2* __restrict__ dst) {
    int g  = blockIdx.x;
    int f  = g & 7;
    int vb = g >> 3;
    const uint2* __restrict__ s = src + (size_t)f * NV;
    uint2*       __restrict__ d = dst + (size_t)f * NV;

    int l   = vb * 256 + threadIdx.x;
    int i   = l / DIM2;
    int rem = l % DIM2;
    int j   = rem / DIM;
    int k   = rem % DIM;

    H4 v; v.u = s[l];
    float2 vxy = __half22float2(v.h2[0]);
    float  vz  = __low2float(v.h2[1]);

    TriP t = tri_prep((float)i + vxy.x, (float)j + vxy.y, (float)k + vz);
    H8 c[4];
    tri_gather_global(s, t, c);
    H2P smp = tri_combine(t, c);

    H4 o;
    o.h2[0] = __hadd2(v.h2[0], smp.xy);
    o.h2[1] = __hadd2(v.h2[1], smp.z);
    d[l] = o.u;
}

// Compose + residual + loss for all 6 pairs, one thread per voxel.
__global__ __launch_bounds__(256) void loss_kernel(const uint2* __restrict__ fields,
                                                   const float* __restrict__ R,
                                                   float* __restrict__ out) {
    int l = blockIdx.x * 256 + threadIdx.x;
    int k = l % DIM;
    int j = (l / DIM) % DIM;
    int i = l / DIM2;
    float fi = (float)i, fj = (float)j, fk = (float)k;

    H4 f1c[3];
    #pragma unroll
    for (int r = 0; r < 3; r++)
        f1c[r].u = fields[(size_t)(4 + r) * NV + l];

    float rbuf[18];
    const float* Rl = R + (size_t)l * 18;
    #pragma unroll
    for (int q = 0; q < 18; q++) rbuf[q] = Rl[q];

    const int REFI[6] = {0, 0, 0, 1, 1, 2};
    const int FLOI[6] = {1, 2, 3, 2, 3, 3};

    float acc = 0.0f;
    #pragma unroll
    for (int p = 0; p < 6; p++) {
        H4 f1 = f1c[REFI[p]];
        float2 f1xy = __half22float2(f1.h2[0]);
        float  f1z  = __low2float(f1.h2[1]);
        const uint2* __restrict__ f2 = fields + (size_t)FLOI[p] * NV;
        TriP t = tri_prep(fi + f1xy.x, fj + f1xy.y, fk + f1z);
        H8 c[4];
        tri_gather_global(f2, t, c);
        H2P s = tri_combine(t, c);
        __half2 hxy = __hadd2(f1.h2[0], s.xy);
        __half2 hz  = __hadd2(f1.h2[1], s.z);
        float2 sxy = __half22float2(hxy);
        float  sz  = __low2float(hz);
        float rx = sxy.x - rbuf[0 * 6 + p];
        float ry = sxy.y - rbuf[1 * 6 + p];
        float rz = sz    - rbuf[2 * 6 + p];
        acc += sqrtf(rx * rx + ry * ry + rz * rz);
    }

    __shared__ float wsum[4];
    int lane = threadIdx.x & 63;
    int wid  = threadIdx.x >> 6;
    #pragma unroll
    for (int off = 32; off > 0; off >>= 1)
        acc += __shfl_down(acc, off, 64);
    if (lane == 0) wsum[wid] = acc;
    __syncthreads();
    if (threadIdx.x == 0) {
        float s = wsum[0] + wsum[1] + wsum[2] + wsum[3];
        atomicAdd(out, s);
    }
}

extern "C" void kernel_launch(void* const* d_in, const int* in_sizes, int n_in,
                              void* d_out, int out_size, void* d_ws, size_t ws_size,
                              hipStream_t stream) {
    const float* T = (const float*)d_in[0];   // (4,3,96,96,96) fp32
    const float* R = (const float*)d_in[1];   // (96,96,96,3,6) fp32
    float* out = (float*)d_out;               // scalar loss

    // Two ping-pong buffers of 8 half4 fields (56.6 MB each) + 16B-gather slack.
    uint2* bufA = (uint2*)d_ws;
    uint2* bufB = bufA + (size_t)8 * NV + 32;

    dim3 blk(256);
    init_kernel<<<dim3(NB, 4), blk, 0, stream>>>(T, bufA, out);

    uint2* src = bufA;
    uint2* dst = bufB;
    // Displacement bound at input of step s ~= 2^s/128 * max|v| (max|v|~5.2):
    // s0-s4 <= 0.65 -> H=1; s5 <= 1.3 -> H=2; s6 <= 2.6 -> plain gathers.
    // Fallback path covers any violation.
    for (int s = 0; s < 5; s++) {
        // tiles: 6(x) * 8(y, CY=12) * 6(z) * 8 fields = 2304 blocks
        step_col_kernel<1, 12><<<6 * 8 * 6 * 8, blk, 0, stream>>>(src, dst);
        uint2* tmp = src; src = dst; dst = tmp;
    }
    // tiles: 6 * 12(CY=8) * 6 * 8 = 3456 blocks
    step_col_kernel<2, 8><<<6 * 12 * 6 * 8, blk, 0, stream>>>(src, dst);
    { uint2* tmp = src; src = dst; dst = tmp; }
    step_plain_kernel<<<NB * 8, blk, 0, stream>>>(src, dst);
    { uint2* tmp = src; src = dst; dst = tmp; }

    loss_kernel<<<NB, blk, 0, stream>>>(src, R, out);
}